// Round 5
// baseline (144.045 us; speedup 1.0000x reference)
//
#include <hip/hip_runtime.h>

#define CCH 192
#define HWN 16384
#define NB  4
#define SPLIT 16

typedef __attribute__((ext_vector_type(8))) short bf16x8;
typedef __attribute__((ext_vector_type(4))) float f32x4;

__device__ __forceinline__ ushort f2bf(float f) {
  union { float f; unsigned u; } v; v.f = f;
  return (ushort)((v.u + 0x7fffu + ((v.u >> 16) & 1u)) >> 16);
}

__device__ __forceinline__ float wsum(float v) {
#pragma unroll
  for (int off = 32; off > 0; off >>= 1) v += __shfl_xor(v, off, 64);
  return v;
}
__device__ __forceinline__ float wmax(float v) {
#pragma unroll
  for (int off = 32; off > 0; off >>= 1) v = fmaxf(v, __shfl_xor(v, off, 64));
  return v;
}

// K0: Wqkv f32 [c][576] -> Wb bf16 [j][c] (j-major), 64x64 LDS transpose tiles
__global__ __launch_bounds__(256) void k0_wconv(const float* __restrict__ Wqkv, ushort* __restrict__ Wb) {
  int j0 = blockIdx.x * 64, c0 = blockIdx.y * 64;
  __shared__ float L[64][65];
  int t = threadIdx.x;
#pragma unroll
  for (int p = 0; p < 4; ++p) {
    int idx = t + 256 * p;
    int row = idx >> 4, col = (idx & 15) << 2;   // row = c, col = j
    float4 v = *reinterpret_cast<const float4*>(&Wqkv[(size_t)(c0 + row) * 576 + j0 + col]);
    L[row][col] = v.x; L[row][col + 1] = v.y; L[row][col + 2] = v.z; L[row][col + 3] = v.w;
  }
  __syncthreads();
#pragma unroll
  for (int p = 0; p < 4; ++p) {
    int idx = t + 256 * p;
    int jrow = idx >> 4, c4 = (idx & 15) << 2;
    ushort4 o;
    o.x = f2bf(L[c4 + 0][jrow]);
    o.y = f2bf(L[c4 + 1][jrow]);
    o.z = f2bf(L[c4 + 2][jrow]);
    o.w = f2bf(L[c4 + 3][jrow]);
    *reinterpret_cast<ushort4*>(&Wb[(size_t)(j0 + jrow) * CCH + c0 + c4]) = o;
  }
}

// K1: x[c][n] f32 -> xT[n][c] bf16, 64x64 LDS tiles
__global__ __launch_bounds__(256) void k1_xpose(const float* __restrict__ x, ushort* __restrict__ xT) {
  int z = blockIdx.z;
  const float* xb = x + (size_t)z * CCH * HWN;
  ushort* xTb = xT + (size_t)z * HWN * CCH;
  int n0 = blockIdx.x * 64, c0 = blockIdx.y * 64;
  __shared__ float L[64][65];
  int t = threadIdx.x;
#pragma unroll
  for (int p = 0; p < 4; ++p) {
    int idx = t + 256 * p;
    int row = idx >> 4, col = (idx & 15) << 2;
    float4 v = *reinterpret_cast<const float4*>(&xb[(size_t)(c0 + row) * HWN + n0 + col]);
    L[row][col] = v.x; L[row][col + 1] = v.y; L[row][col + 2] = v.z; L[row][col + 3] = v.w;
  }
  __syncthreads();
#pragma unroll
  for (int p = 0; p < 4; ++p) {
    int idx = t + 256 * p;
    int nl = idx >> 4, c4 = (idx & 15) << 2;
    ushort4 o;
    o.x = f2bf(L[c4 + 0][nl]);
    o.y = f2bf(L[c4 + 1][nl]);
    o.z = f2bf(L[c4 + 2][nl]);
    o.w = f2bf(L[c4 + 3][nl]);
    *reinterpret_cast<ushort4*>(&xTb[(size_t)(n0 + nl) * CCH + c0 + c4]) = o;
  }
}

// K2: qkv GEMM. D[n][j] = sum_c xT[n][c] * Wb[j][c].  W fragments in registers.
// Epilogues go through LDS transpose for wide coalesced global stores.
__global__ __launch_bounds__(256) void k2_qkv(
    const ushort* __restrict__ xT, const ushort* __restrict__ Wb,
    ushort* __restrict__ Tqk, ushort* __restrict__ Vt, float* __restrict__ norm2p)
{
  int z = blockIdx.z;
  const ushort* xTb = xT + (size_t)z * HWN * CCH;
  ushort* Tb = Tqk + (size_t)z * 384 * HWN;
  ushort* Vb = Vt + (size_t)z * HWN * CCH;
  float* npb = norm2p + (size_t)z * 256 * 384;
  int nt = blockIdx.x, jt = blockIdx.y;
  int n0 = nt * 128, j0 = jt * 64;
  __shared__ __align__(16) ushort As[13312];   // 26624 B; epilogue buffers overlay
  int t = threadIdx.x, l = t & 63, w = t >> 6;
  int wn = w >> 1, wj = w & 1, lg = l >> 4, lr = l & 15;
  bf16x8 bfrag[2][3][2];
#pragma unroll
  for (int h = 0; h < 2; ++h)
#pragma unroll
    for (int k3 = 0; k3 < 3; ++k3)
#pragma unroll
      for (int f = 0; f < 2; ++f)
        bfrag[h][k3][f] = *reinterpret_cast<const bf16x8*>(
            &Wb[(size_t)(j0 + 32 * wj + 16 * f + lr) * CCH + 96 * h + 32 * k3 + 8 * lg]);
  f32x4 acc[4][2] = {};
  for (int h = 0; h < 2; ++h) {
    if (h) __syncthreads();
    for (int i = t; i < 128 * 12; i += 256) {
      int row = i / 12, slot = i % 12;
      *reinterpret_cast<int4*>(&As[row * 104 + slot * 8]) =
          *reinterpret_cast<const int4*>(&xTb[(size_t)(n0 + row) * CCH + 96 * h + slot * 8]);
    }
    __syncthreads();
#pragma unroll
    for (int k3 = 0; k3 < 3; ++k3) {
      bf16x8 a[4];
#pragma unroll
      for (int m = 0; m < 4; ++m)
        a[m] = *reinterpret_cast<const bf16x8*>(&As[(64 * wn + 16 * m + lr) * 104 + k3 * 32 + lg * 8]);
#pragma unroll
      for (int m = 0; m < 4; ++m)
#pragma unroll
        for (int f = 0; f < 2; ++f)
          acc[m][f] = __builtin_amdgcn_mfma_f32_16x16x32_bf16(a[m], bfrag[h][k3][f], acc[m][f], 0, 0, 0);
    }
  }
  if (jt >= 6) {
    // V path: acc(n=64wn+16m+4lg+r, c=32wj+16f+lr) -> LDS [128 n][72 c] -> wide stores
    __syncthreads();
    ushort* Vep = As;  // 128*72*2 = 18432 B
#pragma unroll
    for (int m = 0; m < 4; ++m)
#pragma unroll
      for (int f = 0; f < 2; ++f) {
        int cl = 32 * wj + 16 * f + lr;
#pragma unroll
        for (int r = 0; r < 4; ++r)
          Vep[(64 * wn + 16 * m + 4 * lg + r) * 72 + cl] = f2bf(acc[m][f][r]);
      }
    __syncthreads();
    int cb0 = (jt - 6) * 64;
#pragma unroll
    for (int p = 0; p < 4; ++p) {
      int nl = p * 32 + (t >> 3), ch = t & 7;
      int4 v = *reinterpret_cast<const int4*>(&Vep[nl * 72 + ch * 8]);
      *reinterpret_cast<int4*>(&Vb[(size_t)(n0 + nl) * CCH + cb0 + ch * 8]) = v;
    }
  } else {
    // q/k path: norm partials from regs, then LDS [64 j][136 n] -> 256B row stores
    int jb = j0 + 32 * wj;
#pragma unroll
    for (int f = 0; f < 2; ++f) {
      float sq = 0.f;
      int j = jb + 16 * f + lr;
#pragma unroll
      for (int m = 0; m < 4; ++m)
#pragma unroll
        for (int r = 0; r < 4; ++r) sq += acc[m][f][r] * acc[m][f][r];
      sq += __shfl_xor(sq, 16, 64);
      sq += __shfl_xor(sq, 32, 64);
      if (lg == 0) npb[(size_t)(2 * nt + wn) * 384 + j] = sq;
    }
    __syncthreads();
    ushort* Ep = As;  // 64*136*2 = 17408 B
#pragma unroll
    for (int m = 0; m < 4; ++m)
#pragma unroll
      for (int f = 0; f < 2; ++f) {
        int jl = 32 * wj + 16 * f + lr;
        int nb = 64 * wn + 16 * m + 4 * lg;
        unsigned p0 = (unsigned)f2bf(acc[m][f][0]) | ((unsigned)f2bf(acc[m][f][1]) << 16);
        unsigned p1 = (unsigned)f2bf(acc[m][f][2]) | ((unsigned)f2bf(acc[m][f][3]) << 16);
        *reinterpret_cast<unsigned*>(&Ep[jl * 136 + nb]) = p0;
        *reinterpret_cast<unsigned*>(&Ep[jl * 136 + nb + 2]) = p1;
      }
    __syncthreads();
#pragma unroll
    for (int p = 0; p < 4; ++p) {
      int jl = p * 16 + (t >> 4), ch = t & 15;
      int4 v = *reinterpret_cast<const int4*>(&Ep[jl * 136 + ch * 8]);
      *reinterpret_cast<int4*>(&Tb[(size_t)(j0 + jl) * HWN + n0 + ch * 8]) = v;
    }
  }
}

// K3: invn[j] = 1/max(sqrt(sum_nb norm2p[nb][j]), eps)
__global__ __launch_bounds__(256) void k3_invn(const float* __restrict__ norm2p, float* __restrict__ invn) {
  int z = blockIdx.y, j = blockIdx.x;
  const float* npb = norm2p + (size_t)z * 256 * 384;
  int t = threadIdx.x;
  float s = npb[(size_t)t * 384 + j];
  s = wsum(s);
  __shared__ float red[4];
  if ((t & 63) == 0) red[t >> 6] = s;
  __syncthreads();
  if (t == 0) {
    float tot = red[0] + red[1] + red[2] + red[3];
    invn[(size_t)z * 384 + j] = 1.f / fmaxf(sqrtf(tot), 1e-12f);
  }
}

// K4: Gpart[chunk][c][d] = sum over n-chunk of K[c][n]*Q[d][n], bf16 MFMA
__global__ __launch_bounds__(256) void k4_gram(const ushort* __restrict__ Tqk, float* __restrict__ Gpart) {
  int z = blockIdx.z;
  const ushort* Tb = Tqk + (size_t)z * 384 * HWN;
  float* Gb = Gpart + (size_t)z * SPLIT * CCH * CCH;
  int tile = blockIdx.x, chunk = blockIdx.y;
  int ct = tile / 3, dt = tile % 3;
  __shared__ __align__(16) ushort Ks[64 * 72];
  __shared__ __align__(16) ushort Qs[64 * 72];
  int t = threadIdx.x, l = t & 63, w = t >> 6;
  int wc = w >> 1, wd = w & 1, lg = l >> 4, lr = l & 15;
  f32x4 acc[2][2] = {};
  for (int s = 0; s < 16; ++s) {
    int nb = chunk * 1024 + s * 64;
    for (int i = t; i < 512; i += 256) {
      int row = i >> 3, sl = i & 7;
      *reinterpret_cast<int4*>(&Ks[row * 72 + sl * 8]) =
          *reinterpret_cast<const int4*>(&Tb[(size_t)(192 + ct * 64 + row) * HWN + nb + sl * 8]);
      *reinterpret_cast<int4*>(&Qs[row * 72 + sl * 8]) =
          *reinterpret_cast<const int4*>(&Tb[(size_t)(dt * 64 + row) * HWN + nb + sl * 8]);
    }
    __syncthreads();
#pragma unroll
    for (int hh = 0; hh < 2; ++hh) {
      bf16x8 a[2], bb[2];
#pragma unroll
      for (int m = 0; m < 2; ++m)
        a[m] = *reinterpret_cast<const bf16x8*>(&Ks[(32 * wc + 16 * m + lr) * 72 + hh * 32 + lg * 8]);
#pragma unroll
      for (int f = 0; f < 2; ++f)
        bb[f] = *reinterpret_cast<const bf16x8*>(&Qs[(32 * wd + 16 * f + lr) * 72 + hh * 32 + lg * 8]);
#pragma unroll
      for (int m = 0; m < 2; ++m)
#pragma unroll
        for (int f = 0; f < 2; ++f)
          acc[m][f] = __builtin_amdgcn_mfma_f32_16x16x32_bf16(a[m], bb[f], acc[m][f], 0, 0, 0);
    }
    __syncthreads();
  }
#pragma unroll
  for (int m = 0; m < 2; ++m)
#pragma unroll
    for (int f = 0; f < 2; ++f)
#pragma unroll
      for (int r = 0; r < 4; ++r)
        Gb[(size_t)(chunk * CCH + ct * 64 + 32 * wc + 16 * m + 4 * lg + r) * CCH +
           dt * 64 + 32 * wd + 16 * f + lr] = acc[m][f][r];
}

// K5: reduce Gpart over chunks, scale, softmax over d -> S
__global__ __launch_bounds__(64) void k5_softmax(
    const float* __restrict__ Gpart, const float* __restrict__ invn,
    const float* __restrict__ sigma, float* __restrict__ S)
{
  int c = blockIdx.x, z = blockIdx.y;
  const float* Gb = Gpart + (size_t)z * SPLIT * CCH * CCH;
  const float* inb = invn + (size_t)z * 384;
  float sig = sigma[0];
  float ink = inb[192 + c];
  float lv[3];
#pragma unroll
  for (int r = 0; r < 3; ++r) {
    int d = threadIdx.x + 64 * r;
    float s = 0.f;
    for (int ch = 0; ch < SPLIT; ++ch)
      s += Gb[(size_t)(ch * CCH + c) * CCH + d];
    lv[r] = s * ink * inb[d] * sig;
  }
  float m = fmaxf(lv[0], fmaxf(lv[1], lv[2]));
  m = wmax(m);
  float e[3], tot = 0.f;
#pragma unroll
  for (int r = 0; r < 3; ++r) { e[r] = __expf(lv[r] - m); tot += e[r]; }
  tot = wsum(tot);
  float inv = 1.f / tot;
  float* Sb = S + (size_t)z * CCH * CCH;
#pragma unroll
  for (int r = 0; r < 3; ++r) Sb[(size_t)c * CCH + threadIdx.x + 64 * r] = e[r] * inv;
}

// K6: Mt[e][c] = sum_d S[c][d] * Wlin[d][e]  (bf16 out, transposed for K7)
__global__ __launch_bounds__(192) void k6_mlin(
    const float* __restrict__ S, const float* __restrict__ Wlin, ushort* __restrict__ Mt)
{
  int z = blockIdx.y, c = blockIdx.x, e = threadIdx.x;
  const float* Sb = S + (size_t)z * CCH * CCH;
  float s = 0.f;
  for (int d = 0; d < CCH; ++d) s += Sb[(size_t)c * CCH + d] * Wlin[(size_t)d * CCH + e];
  Mt[(size_t)z * CCH * CCH + (size_t)e * CCH + c] = f2bf(s);
}

// K7: out[e][n] = sum_c Mt[e][c] * Vt[n][c].  V = A-operand so acc regs hold
// 4 consecutive n -> direct aligned float4 stores.
__global__ __launch_bounds__(256) void k7_out(
    const ushort* __restrict__ Mt, const ushort* __restrict__ Vt, float* __restrict__ out)
{
  int z = blockIdx.z;
  const ushort* Mb = Mt + (size_t)z * CCH * CCH;
  const ushort* Vb = Vt + (size_t)z * HWN * CCH;
  float* ob = out + (size_t)z * CCH * HWN;
  int nt = blockIdx.x, et = blockIdx.y;
  int e0 = et * 64, n0 = nt * 128;
  __shared__ __align__(16) ushort Vs[128 * 104];
  int t = threadIdx.x, l = t & 63, w = t >> 6;
  int wn = w >> 1, we = w & 1, lg = l >> 4, lr = l & 15;
  bf16x8 mfrag[2][3][2];
#pragma unroll
  for (int h = 0; h < 2; ++h)
#pragma unroll
    for (int k3 = 0; k3 < 3; ++k3)
#pragma unroll
      for (int mg = 0; mg < 2; ++mg)
        mfrag[h][k3][mg] = *reinterpret_cast<const bf16x8*>(
            &Mb[(size_t)(e0 + 32 * we + 16 * mg + lr) * CCH + 96 * h + 32 * k3 + 8 * lg]);
  f32x4 acc[4][2] = {};   // [ng][mg]: n = 64wn+16ng+4lg+r, e = 32we+16mg+lr
  for (int h = 0; h < 2; ++h) {
    if (h) __syncthreads();
    for (int i = t; i < 128 * 12; i += 256) {
      int row = i / 12, slot = i % 12;
      *reinterpret_cast<int4*>(&Vs[row * 104 + slot * 8]) =
          *reinterpret_cast<const int4*>(&Vb[(size_t)(n0 + row) * CCH + 96 * h + slot * 8]);
    }
    __syncthreads();
#pragma unroll
    for (int k3 = 0; k3 < 3; ++k3) {
      bf16x8 an[4];
#pragma unroll
      for (int ng = 0; ng < 4; ++ng)
        an[ng] = *reinterpret_cast<const bf16x8*>(&Vs[(64 * wn + 16 * ng + lr) * 104 + k3 * 32 + lg * 8]);
#pragma unroll
      for (int ng = 0; ng < 4; ++ng)
#pragma unroll
        for (int mg = 0; mg < 2; ++mg)
          acc[ng][mg] = __builtin_amdgcn_mfma_f32_16x16x32_bf16(an[ng], mfrag[h][k3][mg], acc[ng][mg], 0, 0, 0);
    }
  }
#pragma unroll
  for (int ng = 0; ng < 4; ++ng)
#pragma unroll
    for (int mg = 0; mg < 2; ++mg)
      *reinterpret_cast<f32x4*>(
          &ob[(size_t)(e0 + 32 * we + 16 * mg + lr) * HWN + n0 + 64 * wn + 16 * ng + 4 * lg]) = acc[ng][mg];
}

extern "C" void kernel_launch(void* const* d_in, const int* in_sizes, int n_in,
                              void* d_out, int out_size, void* d_ws, size_t ws_size,
                              hipStream_t stream) {
  const float* x     = (const float*)d_in[0];
  const float* Wqkv  = (const float*)d_in[1];
  const float* Wlin  = (const float*)d_in[2];
  const float* sigma = (const float*)d_in[3];
  float* out = (float*)d_out;

  const size_t wbElems = (size_t)576 * CCH;
  const size_t perB =
      (size_t)HWN * CCH * 2 +
      (size_t)384 * HWN * 2 +
      (size_t)HWN * CCH * 2 +
      (size_t)256 * 384 * 4 +
      (size_t)384 * 4 +
      (size_t)SPLIT * CCH * CCH * 4 +
      (size_t)CCH * CCH * 4 +
      (size_t)CCH * CCH * 2;
  int per = (ws_size >= wbElems * 2 + (size_t)NB * perB) ? NB : 1;

  ushort* Wb = (ushort*)d_ws;
  k0_wconv<<<dim3(9, 3), 256, 0, stream>>>(Wqkv, Wb);

  for (int b0 = 0; b0 < NB; b0 += per) {
    char* base = (char*)d_ws + wbElems * 2;
    ushort* xT   = (ushort*)base;
    ushort* Tqk  = xT + (size_t)per * HWN * CCH;
    ushort* Vt   = Tqk + (size_t)per * 384 * HWN;
    float* norm2p = (float*)(Vt + (size_t)per * HWN * CCH);
    float* invn  = norm2p + (size_t)per * 256 * 384;
    float* Gpart = invn + (size_t)per * 384;
    float* S     = Gpart + (size_t)per * SPLIT * CCH * CCH;
    ushort* Mt   = (ushort*)(S + (size_t)per * CCH * CCH);
    const float* xb = x + (size_t)b0 * CCH * HWN;
    float* ob = out + (size_t)b0 * CCH * HWN;

    k1_xpose  <<<dim3(256, 3, per), 256, 0, stream>>>(xb, xT);
    k2_qkv    <<<dim3(128, 9, per), 256, 0, stream>>>(xT, Wb, Tqk, Vt, norm2p);
    k3_invn   <<<dim3(384, per), 256, 0, stream>>>(norm2p, invn);
    k4_gram   <<<dim3(9, SPLIT, per), 256, 0, stream>>>(Tqk, Gpart);
    k5_softmax<<<dim3(192, per), 64, 0, stream>>>(Gpart, invn, sigma, S);
    k6_mlin   <<<dim3(192, per), 192, 0, stream>>>(S, Wlin, Mt);
    k7_out    <<<dim3(128, 3, per), 256, 0, stream>>>(Mt, Vt, ob);
  }
}

// Round 6
// 131.647 us; speedup vs baseline: 1.0942x; 1.0942x over previous
//
#include <hip/hip_runtime.h>

#define CCH 192
#define HWN 16384
#define NB  4
#define SPLIT 16

typedef __attribute__((ext_vector_type(8))) short bf16x8;
typedef __attribute__((ext_vector_type(4))) float f32x4;

// swizzled fragment-native layout for a [R rows][C cols] bf16 matrix:
//   idx(r,c) = (r>>4)*(16*C) + (c>>3)*128 + (r&15)*8 + (c&7)
// frag load (16 rows r0+lr, 8 cols cb+8lg) = one contiguous 1KB wave segment.

__device__ __forceinline__ ushort f2bf(float f) {
  union { float f; unsigned u; } v; v.f = f;
  return (ushort)((v.u + 0x7fffu + ((v.u >> 16) & 1u)) >> 16);
}

__device__ __forceinline__ float wsum(float v) {
#pragma unroll
  for (int off = 32; off > 0; off >>= 1) v += __shfl_xor(v, off, 64);
  return v;
}
__device__ __forceinline__ float wmax(float v) {
#pragma unroll
  for (int off = 32; off > 0; off >>= 1) v = fmaxf(v, __shfl_xor(v, off, 64));
  return v;
}

// K0: Wqkv f32 [c][576] -> Wb bf16 [j][c] row-major (tiny, register-preloaded later)
__global__ __launch_bounds__(256) void k0_wconv(const float* __restrict__ Wqkv, ushort* __restrict__ Wb) {
  int j0 = blockIdx.x * 64, c0 = blockIdx.y * 64;
  __shared__ float L[64][65];
  int t = threadIdx.x;
#pragma unroll
  for (int p = 0; p < 4; ++p) {
    int idx = t + 256 * p;
    int row = idx >> 4, col = (idx & 15) << 2;   // row = c, col = j
    float4 v = *reinterpret_cast<const float4*>(&Wqkv[(size_t)(c0 + row) * 576 + j0 + col]);
    L[row][col] = v.x; L[row][col + 1] = v.y; L[row][col + 2] = v.z; L[row][col + 3] = v.w;
  }
  __syncthreads();
#pragma unroll
  for (int p = 0; p < 4; ++p) {
    int idx = t + 256 * p;
    int jrow = idx >> 4, c4 = (idx & 15) << 2;
    ushort4 o;
    o.x = f2bf(L[c4 + 0][jrow]);
    o.y = f2bf(L[c4 + 1][jrow]);
    o.z = f2bf(L[c4 + 2][jrow]);
    o.w = f2bf(L[c4 + 3][jrow]);
    *reinterpret_cast<ushort4*>(&Wb[(size_t)(j0 + jrow) * CCH + c0 + c4]) = o;
  }
}

// K1: x[c][n] f32 -> xT2 swizzled-frag bf16 (rows=n, cols=c), 64x64 LDS tiles
__global__ __launch_bounds__(256) void k1_xpose(const float* __restrict__ x, ushort* __restrict__ xT2) {
  int z = blockIdx.z;
  const float* xb = x + (size_t)z * CCH * HWN;
  ushort* xb2 = xT2 + (size_t)z * HWN * CCH;
  int n0 = blockIdx.x * 64, c0 = blockIdx.y * 64;
  __shared__ float L[64][65];   // [c_local][n_local]
  int t = threadIdx.x;
#pragma unroll
  for (int p = 0; p < 4; ++p) {
    int idx = t + 256 * p;
    int row = idx >> 4, col = (idx & 15) << 2;
    float4 v = *reinterpret_cast<const float4*>(&xb[(size_t)(c0 + row) * HWN + n0 + col]);
    L[row][col] = v.x; L[row][col + 1] = v.y; L[row][col + 2] = v.z; L[row][col + 3] = v.w;
  }
  __syncthreads();
#pragma unroll
  for (int p = 0; p < 2; ++p) {
    int idx = t + 256 * p;                 // 0..511 = 16 nq x 8 cg x 4 n16
    int nq = idx & 15, cg = (idx >> 4) & 7, n16 = idx >> 7;
    int nl = n16 * 16 + nq;
    unsigned u0 = (unsigned)f2bf(L[cg * 8 + 0][nl]) | ((unsigned)f2bf(L[cg * 8 + 1][nl]) << 16);
    unsigned u1 = (unsigned)f2bf(L[cg * 8 + 2][nl]) | ((unsigned)f2bf(L[cg * 8 + 3][nl]) << 16);
    unsigned u2 = (unsigned)f2bf(L[cg * 8 + 4][nl]) | ((unsigned)f2bf(L[cg * 8 + 5][nl]) << 16);
    unsigned u3 = (unsigned)f2bf(L[cg * 8 + 6][nl]) | ((unsigned)f2bf(L[cg * 8 + 7][nl]) << 16);
    size_t off = (size_t)((n0 >> 4) + n16) * (16 * CCH) + ((c0 >> 3) + cg) * 128 + nq * 8;
    *reinterpret_cast<int4*>(&xb2[off]) = make_int4(u0, u1, u2, u3);
  }
}

// K2: qkv GEMM, LDS-free main loop. D[n][j] = sum_c xT2[n][c] * Wb[j][c].
// jt 0..5 -> Tqk2 (swizzled, rows=j, cols=n) + norm2 partials; jt 6..8 -> Vt2 (swizzled, rows=n, cols=c).
__global__ __launch_bounds__(256) void k2_qkv(
    const ushort* __restrict__ xT2, const ushort* __restrict__ Wb,
    ushort* __restrict__ Tqk2, ushort* __restrict__ Vt2, float* __restrict__ norm2p)
{
  int z = blockIdx.z;
  const ushort* xb2 = xT2 + (size_t)z * HWN * CCH;
  ushort* Tb2 = Tqk2 + (size_t)z * 384 * HWN;
  ushort* Vb2 = Vt2 + (size_t)z * HWN * CCH;
  float* npb = norm2p + (size_t)z * 256 * 384;
  int nt = blockIdx.x, jt = blockIdx.y;
  int n0 = nt * 128, j0 = jt * 64;
  __shared__ __align__(16) ushort Ep[9216];   // 18432 B, epilogue only
  int t = threadIdx.x, l = t & 63, w = t >> 6;
  int wn = w >> 1, wj = w & 1, lg = l >> 4, lr = l & 15;
  int nblk = n0 >> 4;
  bf16x8 bfrag[2][3][2];
#pragma unroll
  for (int h = 0; h < 2; ++h)
#pragma unroll
    for (int k3 = 0; k3 < 3; ++k3)
#pragma unroll
      for (int f = 0; f < 2; ++f)
        bfrag[h][k3][f] = *reinterpret_cast<const bf16x8*>(
            &Wb[(size_t)(j0 + 32 * wj + 16 * f + lr) * CCH + 96 * h + 32 * k3 + 8 * lg]);
  f32x4 acc[4][2] = {};
#pragma unroll
  for (int h = 0; h < 2; ++h)
#pragma unroll
    for (int k3 = 0; k3 < 3; ++k3) {
      bf16x8 a[4];
#pragma unroll
      for (int m = 0; m < 4; ++m)
        a[m] = *reinterpret_cast<const bf16x8*>(
            &xb2[(size_t)(nblk + 4 * wn + m) * (16 * CCH) + (12 * h + 4 * k3 + lg) * 128 + lr * 8]);
#pragma unroll
      for (int m = 0; m < 4; ++m)
#pragma unroll
        for (int f = 0; f < 2; ++f)
          acc[m][f] = __builtin_amdgcn_mfma_f32_16x16x32_bf16(a[m], bfrag[h][k3][f], acc[m][f], 0, 0, 0);
    }
  if (jt >= 6) {
    // V: acc(n = 64wn+16m+4lg+r, c = 32wj+16f+lr) -> Ep[128 n][72 c] -> swizzled Vt2
#pragma unroll
    for (int m = 0; m < 4; ++m)
#pragma unroll
      for (int f = 0; f < 2; ++f) {
        int cl = 32 * wj + 16 * f + lr;
#pragma unroll
        for (int r = 0; r < 4; ++r)
          Ep[(64 * wn + 16 * m + 4 * lg + r) * 72 + cl] = f2bf(acc[m][f][r]);
      }
    __syncthreads();
    int cb8 = (jt - 6) * 8;                  // c-base / 8
#pragma unroll
    for (int p = 0; p < 4; ++p) {
      int idx = t + 256 * p;                 // 0..1023 = 16 nq x 8 cg x 8 n16
      int nq = idx & 15, cg = (idx >> 4) & 7, n16 = idx >> 7;
      int4 v = *reinterpret_cast<const int4*>(&Ep[(n16 * 16 + nq) * 72 + cg * 8]);
      size_t off = (size_t)(nblk + n16) * (16 * CCH) + (cb8 + cg) * 128 + nq * 8;
      *reinterpret_cast<int4*>(&Vb2[off]) = v;
    }
  } else {
    // q/k: norm partials from regs, then Ep[64 j][136 n] -> swizzled Tqk2
    int jb = j0 + 32 * wj;
#pragma unroll
    for (int f = 0; f < 2; ++f) {
      float sq = 0.f;
      int j = jb + 16 * f + lr;
#pragma unroll
      for (int m = 0; m < 4; ++m)
#pragma unroll
        for (int r = 0; r < 4; ++r) sq += acc[m][f][r] * acc[m][f][r];
      sq += __shfl_xor(sq, 16, 64);
      sq += __shfl_xor(sq, 32, 64);
      if (lg == 0) npb[(size_t)(2 * nt + wn) * 384 + j] = sq;
    }
#pragma unroll
    for (int m = 0; m < 4; ++m)
#pragma unroll
      for (int f = 0; f < 2; ++f) {
        int jl = 32 * wj + 16 * f + lr;
        int nb = 64 * wn + 16 * m + 4 * lg;
        unsigned p0 = (unsigned)f2bf(acc[m][f][0]) | ((unsigned)f2bf(acc[m][f][1]) << 16);
        unsigned p1 = (unsigned)f2bf(acc[m][f][2]) | ((unsigned)f2bf(acc[m][f][3]) << 16);
        *reinterpret_cast<unsigned*>(&Ep[jl * 136 + nb]) = p0;
        *reinterpret_cast<unsigned*>(&Ep[jl * 136 + nb + 2]) = p1;
      }
    __syncthreads();
#pragma unroll
    for (int p = 0; p < 4; ++p) {
      int idx = t + 256 * p;                 // 0..1023 = 16 jq x 16 nc x 4 jb16
      int jq = idx & 15, nc = (idx >> 4) & 15, jb16 = idx >> 8;
      int4 v = *reinterpret_cast<const int4*>(&Ep[(jb16 * 16 + jq) * 136 + nc * 8]);
      size_t off = (size_t)((j0 >> 4) + jb16) * (16 * HWN) + ((n0 >> 3) + nc) * 128 + jq * 8;
      *reinterpret_cast<int4*>(&Tb2[off]) = v;
    }
  }
}

// K3: invn[j] = 1/max(sqrt(sum_nb norm2p[nb][j]), eps)
__global__ __launch_bounds__(256) void k3_invn(const float* __restrict__ norm2p, float* __restrict__ invn) {
  int z = blockIdx.y, j = blockIdx.x;
  const float* npb = norm2p + (size_t)z * 256 * 384;
  int t = threadIdx.x;
  float s = npb[(size_t)t * 384 + j];
  s = wsum(s);
  __shared__ float red[4];
  if ((t & 63) == 0) red[t >> 6] = s;
  __syncthreads();
  if (t == 0) {
    float tot = red[0] + red[1] + red[2] + red[3];
    invn[(size_t)z * 384 + j] = 1.f / fmaxf(sqrtf(tot), 1e-12f);
  }
}

// K4: Gpart[chunk][c][d] = sum over n-chunk of K[c][n]*Q[d][n]. LDS-free, direct frag loads.
__global__ __launch_bounds__(256) void k4_gram(const ushort* __restrict__ Tqk2, float* __restrict__ Gpart) {
  int z = blockIdx.z;
  const ushort* Tb2 = Tqk2 + (size_t)z * 384 * HWN;
  float* Gb = Gpart + (size_t)z * SPLIT * CCH * CCH;
  int tile = blockIdx.x, chunk = blockIdx.y;
  int ct = tile / 3, dt = tile % 3;
  int t = threadIdx.x, l = t & 63, w = t >> 6;
  int wc = w >> 1, wd = w & 1, lg = l >> 4, lr = l & 15;
  f32x4 acc[2][2] = {};
  for (int s = 0; s < 16; ++s) {
    int nco = chunk * 128 + s * 8;           // n-chunk base / 8
#pragma unroll
    for (int hh = 0; hh < 2; ++hh) {
      int ko = nco + 4 * hh + lg;
      bf16x8 a[2], bb[2];
#pragma unroll
      for (int m = 0; m < 2; ++m)
        a[m] = *reinterpret_cast<const bf16x8*>(
            &Tb2[(size_t)(12 + 4 * ct + 2 * wc + m) * (16 * HWN) + ko * 128 + lr * 8]);
#pragma unroll
      for (int f = 0; f < 2; ++f)
        bb[f] = *reinterpret_cast<const bf16x8*>(
            &Tb2[(size_t)(4 * dt + 2 * wd + f) * (16 * HWN) + ko * 128 + lr * 8]);
#pragma unroll
      for (int m = 0; m < 2; ++m)
#pragma unroll
        for (int f = 0; f < 2; ++f)
          acc[m][f] = __builtin_amdgcn_mfma_f32_16x16x32_bf16(a[m], bb[f], acc[m][f], 0, 0, 0);
    }
  }
#pragma unroll
  for (int m = 0; m < 2; ++m)
#pragma unroll
    for (int f = 0; f < 2; ++f)
#pragma unroll
      for (int r = 0; r < 4; ++r)
        Gb[(size_t)(chunk * CCH + ct * 64 + 32 * wc + 16 * m + 4 * lg + r) * CCH +
           dt * 64 + 32 * wd + 16 * f + lr] = acc[m][f][r];
}

// K5: reduce Gpart over chunks, scale, softmax over d -> S
__global__ __launch_bounds__(64) void k5_softmax(
    const float* __restrict__ Gpart, const float* __restrict__ invn,
    const float* __restrict__ sigma, float* __restrict__ S)
{
  int c = blockIdx.x, z = blockIdx.y;
  const float* Gb = Gpart + (size_t)z * SPLIT * CCH * CCH;
  const float* inb = invn + (size_t)z * 384;
  float sig = sigma[0];
  float ink = inb[192 + c];
  float lv[3];
#pragma unroll
  for (int r = 0; r < 3; ++r) {
    int d = threadIdx.x + 64 * r;
    float s = 0.f;
    for (int ch = 0; ch < SPLIT; ++ch)
      s += Gb[(size_t)(ch * CCH + c) * CCH + d];
    lv[r] = s * ink * inb[d] * sig;
  }
  float m = fmaxf(lv[0], fmaxf(lv[1], lv[2]));
  m = wmax(m);
  float e[3], tot = 0.f;
#pragma unroll
  for (int r = 0; r < 3; ++r) { e[r] = __expf(lv[r] - m); tot += e[r]; }
  tot = wsum(tot);
  float inv = 1.f / tot;
  float* Sb = S + (size_t)z * CCH * CCH;
#pragma unroll
  for (int r = 0; r < 3; ++r) Sb[(size_t)c * CCH + threadIdx.x + 64 * r] = e[r] * inv;
}

// K6: Mt[e][c] = sum_d S[c][d] * Wlin[d][e]  (bf16 out, row-major, for K7 B-side)
__global__ __launch_bounds__(192) void k6_mlin(
    const float* __restrict__ S, const float* __restrict__ Wlin, ushort* __restrict__ Mt)
{
  int z = blockIdx.y, c = blockIdx.x, e = threadIdx.x;
  const float* Sb = S + (size_t)z * CCH * CCH;
  float s = 0.f;
  for (int d = 0; d < CCH; ++d) s += Sb[(size_t)c * CCH + d] * Wlin[(size_t)d * CCH + e];
  Mt[(size_t)z * CCH * CCH + (size_t)e * CCH + c] = f2bf(s);
}

// K7: out[e][n] = sum_c Mt[e][c] * Vt2[n][c]. LDS-free: V frags direct from swizzled Vt2.
__global__ __launch_bounds__(256) void k7_out(
    const ushort* __restrict__ Mt, const ushort* __restrict__ Vt2, float* __restrict__ out)
{
  int z = blockIdx.z;
  const ushort* Mb = Mt + (size_t)z * CCH * CCH;
  const ushort* Vb2 = Vt2 + (size_t)z * HWN * CCH;
  float* ob = out + (size_t)z * CCH * HWN;
  int nt = blockIdx.x, et = blockIdx.y;
  int e0 = et * 64, n0 = nt * 128;
  int t = threadIdx.x, l = t & 63, w = t >> 6;
  int wn = w >> 1, we = w & 1, lg = l >> 4, lr = l & 15;
  int nblk = n0 >> 4;
  bf16x8 mfrag[2][3][2];
#pragma unroll
  for (int h = 0; h < 2; ++h)
#pragma unroll
    for (int k3 = 0; k3 < 3; ++k3)
#pragma unroll
      for (int mg = 0; mg < 2; ++mg)
        mfrag[h][k3][mg] = *reinterpret_cast<const bf16x8*>(
            &Mb[(size_t)(e0 + 32 * we + 16 * mg + lr) * CCH + 96 * h + 32 * k3 + 8 * lg]);
  f32x4 acc[4][2] = {};   // [ng][mg]: n = 64wn+16ng+4lg+r, e = 32we+16mg+lr
#pragma unroll
  for (int h = 0; h < 2; ++h)
#pragma unroll
    for (int k3 = 0; k3 < 3; ++k3) {
      bf16x8 an[4];
#pragma unroll
      for (int ng = 0; ng < 4; ++ng)
        an[ng] = *reinterpret_cast<const bf16x8*>(
            &Vb2[(size_t)(nblk + 4 * wn + ng) * (16 * CCH) + (12 * h + 4 * k3 + lg) * 128 + lr * 8]);
#pragma unroll
      for (int ng = 0; ng < 4; ++ng)
#pragma unroll
        for (int mg = 0; mg < 2; ++mg)
          acc[ng][mg] = __builtin_amdgcn_mfma_f32_16x16x32_bf16(an[ng], mfrag[h][k3][mg], acc[ng][mg], 0, 0, 0);
    }
#pragma unroll
  for (int ng = 0; ng < 4; ++ng)
#pragma unroll
    for (int mg = 0; mg < 2; ++mg)
      *reinterpret_cast<f32x4*>(
          &ob[(size_t)(e0 + 32 * we + 16 * mg + lr) * HWN + n0 + 64 * wn + 16 * ng + 4 * lg]) = acc[ng][mg];
}

extern "C" void kernel_launch(void* const* d_in, const int* in_sizes, int n_in,
                              void* d_out, int out_size, void* d_ws, size_t ws_size,
                              hipStream_t stream) {
  const float* x     = (const float*)d_in[0];
  const float* Wqkv  = (const float*)d_in[1];
  const float* Wlin  = (const float*)d_in[2];
  const float* sigma = (const float*)d_in[3];
  float* out = (float*)d_out;

  const size_t wbElems = (size_t)576 * CCH;
  const size_t perB =
      (size_t)HWN * CCH * 2 +          // xT2
      (size_t)384 * HWN * 2 +          // Tqk2
      (size_t)HWN * CCH * 2 +          // Vt2
      (size_t)256 * 384 * 4 +          // norm2p
      (size_t)384 * 4 +                // invn
      (size_t)SPLIT * CCH * CCH * 4 +  // Gpart
      (size_t)CCH * CCH * 4 +          // S
      (size_t)CCH * CCH * 2;           // Mt
  int per = (ws_size >= wbElems * 2 + (size_t)NB * perB) ? NB : 1;

  ushort* Wb = (ushort*)d_ws;
  k0_wconv<<<dim3(9, 3), 256, 0, stream>>>(Wqkv, Wb);

  for (int b0 = 0; b0 < NB; b0 += per) {
    char* base = (char*)d_ws + wbElems * 2;
    ushort* xT2  = (ushort*)base;
    ushort* Tqk2 = xT2 + (size_t)per * HWN * CCH;
    ushort* Vt2  = Tqk2 + (size_t)per * 384 * HWN;
    float* norm2p = (float*)(Vt2 + (size_t)per * HWN * CCH);
    float* invn  = norm2p + (size_t)per * 256 * 384;
    float* Gpart = invn + (size_t)per * 384;
    float* S     = Gpart + (size_t)per * SPLIT * CCH * CCH;
    ushort* Mt   = (ushort*)(S + (size_t)per * CCH * CCH);
    const float* xb = x + (size_t)b0 * CCH * HWN;
    float* ob = out + (size_t)b0 * CCH * HWN;

    k1_xpose  <<<dim3(256, 3, per), 256, 0, stream>>>(xb, xT2);
    k2_qkv    <<<dim3(128, 9, per), 256, 0, stream>>>(xT2, Wb, Tqk2, Vt2, norm2p);
    k3_invn   <<<dim3(384, per), 256, 0, stream>>>(norm2p, invn);
    k4_gram   <<<dim3(9, SPLIT, per), 256, 0, stream>>>(Tqk2, Gpart);
    k5_softmax<<<dim3(192, per), 64, 0, stream>>>(Gpart, invn, sigma, S);
    k6_mlin   <<<dim3(192, per), 192, 0, stream>>>(S, Wlin, Mt);
    k7_out    <<<dim3(128, 3, per), 256, 0, stream>>>(Mt, Vt2, ob);
  }
}

// Round 7
// 128.959 us; speedup vs baseline: 1.1170x; 1.0208x over previous
//
#include <hip/hip_runtime.h>

#define CCH 192
#define HWN 16384
#define NB  4
#define SPLIT 16

typedef __attribute__((ext_vector_type(8))) short bf16x8;
typedef __attribute__((ext_vector_type(4))) float f32x4;

// swizzled fragment-native layout for a [R rows][C cols] bf16 matrix:
//   idx(r,c) = (r>>4)*(16*C) + (c>>3)*128 + (r&15)*8 + (c&7)
// frag load (16 rows r0+lr, 8 cols cb+8lg) = one contiguous 1KB wave segment.

__device__ __forceinline__ ushort f2bf(float f) {
  union { float f; unsigned u; } v; v.f = f;
  return (ushort)((v.u + 0x7fffu + ((v.u >> 16) & 1u)) >> 16);
}

__device__ __forceinline__ float wsum(float v) {
#pragma unroll
  for (int off = 32; off > 0; off >>= 1) v += __shfl_xor(v, off, 64);
  return v;
}
__device__ __forceinline__ float wmax(float v) {
#pragma unroll
  for (int off = 32; off > 0; off >>= 1) v = fmaxf(v, __shfl_xor(v, off, 64));
  return v;
}

// K0: Wqkv f32 [c][576] -> Wb bf16 [j][c] row-major
__global__ __launch_bounds__(256) void k0_wconv(const float* __restrict__ Wqkv, ushort* __restrict__ Wb) {
  int j0 = blockIdx.x * 64, c0 = blockIdx.y * 64;
  __shared__ float L[64][65];
  int t = threadIdx.x;
#pragma unroll
  for (int p = 0; p < 4; ++p) {
    int idx = t + 256 * p;
    int row = idx >> 4, col = (idx & 15) << 2;   // row = c, col = j
    float4 v = *reinterpret_cast<const float4*>(&Wqkv[(size_t)(c0 + row) * 576 + j0 + col]);
    L[row][col] = v.x; L[row][col + 1] = v.y; L[row][col + 2] = v.z; L[row][col + 3] = v.w;
  }
  __syncthreads();
#pragma unroll
  for (int p = 0; p < 4; ++p) {
    int idx = t + 256 * p;
    int jrow = idx >> 4, c4 = (idx & 15) << 2;
    ushort4 o;
    o.x = f2bf(L[c4 + 0][jrow]);
    o.y = f2bf(L[c4 + 1][jrow]);
    o.z = f2bf(L[c4 + 2][jrow]);
    o.w = f2bf(L[c4 + 3][jrow]);
    *reinterpret_cast<ushort4*>(&Wb[(size_t)(j0 + jrow) * CCH + c0 + c4]) = o;
  }
}

// K1: x[c][n] f32 -> xT2 swizzled-frag bf16 (rows=n, cols=c), 64x64 LDS tiles
__global__ __launch_bounds__(256) void k1_xpose(const float* __restrict__ x, ushort* __restrict__ xT2) {
  int z = blockIdx.z;
  const float* xb = x + (size_t)z * CCH * HWN;
  ushort* xb2 = xT2 + (size_t)z * HWN * CCH;
  int n0 = blockIdx.x * 64, c0 = blockIdx.y * 64;
  __shared__ float L[64][65];   // [c_local][n_local]
  int t = threadIdx.x;
#pragma unroll
  for (int p = 0; p < 4; ++p) {
    int idx = t + 256 * p;
    int row = idx >> 4, col = (idx & 15) << 2;
    float4 v = *reinterpret_cast<const float4*>(&xb[(size_t)(c0 + row) * HWN + n0 + col]);
    L[row][col] = v.x; L[row][col + 1] = v.y; L[row][col + 2] = v.z; L[row][col + 3] = v.w;
  }
  __syncthreads();
#pragma unroll
  for (int p = 0; p < 2; ++p) {
    int idx = t + 256 * p;                 // 0..511 = 16 nq x 8 cg x 4 n16
    int nq = idx & 15, cg = (idx >> 4) & 7, n16 = idx >> 7;
    int nl = n16 * 16 + nq;
    unsigned u0 = (unsigned)f2bf(L[cg * 8 + 0][nl]) | ((unsigned)f2bf(L[cg * 8 + 1][nl]) << 16);
    unsigned u1 = (unsigned)f2bf(L[cg * 8 + 2][nl]) | ((unsigned)f2bf(L[cg * 8 + 3][nl]) << 16);
    unsigned u2 = (unsigned)f2bf(L[cg * 8 + 4][nl]) | ((unsigned)f2bf(L[cg * 8 + 5][nl]) << 16);
    unsigned u3 = (unsigned)f2bf(L[cg * 8 + 6][nl]) | ((unsigned)f2bf(L[cg * 8 + 7][nl]) << 16);
    size_t off = (size_t)((n0 >> 4) + n16) * (16 * CCH) + ((c0 >> 3) + cg) * 128 + nq * 8;
    *reinterpret_cast<int4*>(&xb2[off]) = make_int4(u0, u1, u2, u3);
  }
}

// K2: qkv GEMM, LDS-free main path, ALL fragment loads hoisted for max ILP.
// jt 0..5 -> Tqk2 (swizzled, rows=j, cols=n) + norm2 partials; jt 6..8 -> Vt2.
__global__ __launch_bounds__(256, 2) void k2_qkv(
    const ushort* __restrict__ xT2, const ushort* __restrict__ Wb,
    ushort* __restrict__ Tqk2, ushort* __restrict__ Vt2, float* __restrict__ norm2p)
{
  int z = blockIdx.z;
  const ushort* xb2 = xT2 + (size_t)z * HWN * CCH;
  ushort* Tb2 = Tqk2 + (size_t)z * 384 * HWN;
  ushort* Vb2 = Vt2 + (size_t)z * HWN * CCH;
  float* npb = norm2p + (size_t)z * 256 * 384;
  int nt = blockIdx.x, jt = blockIdx.y;
  int n0 = nt * 128, j0 = jt * 64;
  __shared__ __align__(16) ushort Ep[9216];   // 18432 B, epilogue only
  int t = threadIdx.x, l = t & 63, w = t >> 6;
  int wn = w >> 1, wj = w & 1, lg = l >> 4, lr = l & 15;
  int nblk = n0 >> 4;
  // hoist ALL loads (12 bfrag + 24 a-frag), independent -> deep vmcnt pipeline
  bf16x8 bfrag[2][3][2];
#pragma unroll
  for (int h = 0; h < 2; ++h)
#pragma unroll
    for (int k3 = 0; k3 < 3; ++k3)
#pragma unroll
      for (int f = 0; f < 2; ++f)
        bfrag[h][k3][f] = *reinterpret_cast<const bf16x8*>(
            &Wb[(size_t)(j0 + 32 * wj + 16 * f + lr) * CCH + 96 * h + 32 * k3 + 8 * lg]);
  bf16x8 a[2][3][4];
#pragma unroll
  for (int h = 0; h < 2; ++h)
#pragma unroll
    for (int k3 = 0; k3 < 3; ++k3)
#pragma unroll
      for (int m = 0; m < 4; ++m)
        a[h][k3][m] = *reinterpret_cast<const bf16x8*>(
            &xb2[(size_t)(nblk + 4 * wn + m) * (16 * CCH) + (12 * h + 4 * k3 + lg) * 128 + lr * 8]);
  f32x4 acc[4][2] = {};
#pragma unroll
  for (int h = 0; h < 2; ++h)
#pragma unroll
    for (int k3 = 0; k3 < 3; ++k3)
#pragma unroll
      for (int m = 0; m < 4; ++m)
#pragma unroll
        for (int f = 0; f < 2; ++f)
          acc[m][f] = __builtin_amdgcn_mfma_f32_16x16x32_bf16(a[h][k3][m], bfrag[h][k3][f], acc[m][f], 0, 0, 0);
  if (jt >= 6) {
    // V: acc(n = 64wn+16m+4lg+r, c = 32wj+16f+lr) -> Ep[128 n][72 c] -> swizzled Vt2
#pragma unroll
    for (int m = 0; m < 4; ++m)
#pragma unroll
      for (int f = 0; f < 2; ++f) {
        int cl = 32 * wj + 16 * f + lr;
#pragma unroll
        for (int r = 0; r < 4; ++r)
          Ep[(64 * wn + 16 * m + 4 * lg + r) * 72 + cl] = f2bf(acc[m][f][r]);
      }
    __syncthreads();
    int cb8 = (jt - 6) * 8;                  // c-base / 8
#pragma unroll
    for (int p = 0; p < 4; ++p) {
      int idx = t + 256 * p;                 // 0..1023 = 16 nq x 8 cg x 8 n16
      int nq = idx & 15, cg = (idx >> 4) & 7, n16 = idx >> 7;
      int4 v = *reinterpret_cast<const int4*>(&Ep[(n16 * 16 + nq) * 72 + cg * 8]);
      size_t off = (size_t)(nblk + n16) * (16 * CCH) + (cb8 + cg) * 128 + nq * 8;
      *reinterpret_cast<int4*>(&Vb2[off]) = v;
    }
  } else {
    // q/k: norm partials from regs, then Ep[64 j][136 n] -> swizzled Tqk2
    int jb = j0 + 32 * wj;
#pragma unroll
    for (int f = 0; f < 2; ++f) {
      float sq = 0.f;
      int j = jb + 16 * f + lr;
#pragma unroll
      for (int m = 0; m < 4; ++m)
#pragma unroll
        for (int r = 0; r < 4; ++r) sq += acc[m][f][r] * acc[m][f][r];
      sq += __shfl_xor(sq, 16, 64);
      sq += __shfl_xor(sq, 32, 64);
      if (lg == 0) npb[(size_t)(2 * nt + wn) * 384 + j] = sq;
    }
#pragma unroll
    for (int m = 0; m < 4; ++m)
#pragma unroll
      for (int f = 0; f < 2; ++f) {
        int jl = 32 * wj + 16 * f + lr;
        int nb = 64 * wn + 16 * m + 4 * lg;
        unsigned p0 = (unsigned)f2bf(acc[m][f][0]) | ((unsigned)f2bf(acc[m][f][1]) << 16);
        unsigned p1 = (unsigned)f2bf(acc[m][f][2]) | ((unsigned)f2bf(acc[m][f][3]) << 16);
        *reinterpret_cast<unsigned*>(&Ep[jl * 136 + nb]) = p0;
        *reinterpret_cast<unsigned*>(&Ep[jl * 136 + nb + 2]) = p1;
      }
    __syncthreads();
#pragma unroll
    for (int p = 0; p < 4; ++p) {
      int idx = t + 256 * p;                 // 0..1023 = 16 jq x 16 nc x 4 jb16
      int jq = idx & 15, nc = (idx >> 4) & 15, jb16 = idx >> 8;
      int4 v = *reinterpret_cast<const int4*>(&Ep[(jb16 * 16 + jq) * 136 + nc * 8]);
      size_t off = (size_t)((j0 >> 4) + jb16) * (16 * HWN) + ((n0 >> 3) + nc) * 128 + jq * 8;
      *reinterpret_cast<int4*>(&Tb2[off]) = v;
    }
  }
}

// K3: invn[j] = 1/max(sqrt(sum_nb norm2p[nb][j]), eps)
__global__ __launch_bounds__(256) void k3_invn(const float* __restrict__ norm2p, float* __restrict__ invn) {
  int z = blockIdx.y, j = blockIdx.x;
  const float* npb = norm2p + (size_t)z * 256 * 384;
  int t = threadIdx.x;
  float s = npb[(size_t)t * 384 + j];
  s = wsum(s);
  __shared__ float red[4];
  if ((t & 63) == 0) red[t >> 6] = s;
  __syncthreads();
  if (t == 0) {
    float tot = red[0] + red[1] + red[2] + red[3];
    invn[(size_t)z * 384 + j] = 1.f / fmaxf(sqrtf(tot), 1e-12f);
  }
}

// K4: Gpart[chunk][c][d] = sum over n-chunk of K[c][n]*Q[d][n]. LDS-free, direct frag loads.
__global__ __launch_bounds__(256) void k4_gram(const ushort* __restrict__ Tqk2, float* __restrict__ Gpart) {
  int z = blockIdx.z;
  const ushort* Tb2 = Tqk2 + (size_t)z * 384 * HWN;
  float* Gb = Gpart + (size_t)z * SPLIT * CCH * CCH;
  int tile = blockIdx.x, chunk = blockIdx.y;
  int ct = tile / 3, dt = tile % 3;
  int t = threadIdx.x, l = t & 63, w = t >> 6;
  int wc = w >> 1, wd = w & 1, lg = l >> 4, lr = l & 15;
  f32x4 acc[2][2] = {};
  for (int s = 0; s < 16; ++s) {
    int nco = chunk * 128 + s * 8;           // n-chunk base / 8
#pragma unroll
    for (int hh = 0; hh < 2; ++hh) {
      int ko = nco + 4 * hh + lg;
      bf16x8 a[2], bb[2];
#pragma unroll
      for (int m = 0; m < 2; ++m)
        a[m] = *reinterpret_cast<const bf16x8*>(
            &Tb2[(size_t)(12 + 4 * ct + 2 * wc + m) * (16 * HWN) + ko * 128 + lr * 8]);
#pragma unroll
      for (int f = 0; f < 2; ++f)
        bb[f] = *reinterpret_cast<const bf16x8*>(
            &Tb2[(size_t)(4 * dt + 2 * wd + f) * (16 * HWN) + ko * 128 + lr * 8]);
#pragma unroll
      for (int m = 0; m < 2; ++m)
#pragma unroll
        for (int f = 0; f < 2; ++f)
          acc[m][f] = __builtin_amdgcn_mfma_f32_16x16x32_bf16(a[m], bb[f], acc[m][f], 0, 0, 0);
    }
  }
#pragma unroll
  for (int m = 0; m < 2; ++m)
#pragma unroll
    for (int f = 0; f < 2; ++f)
#pragma unroll
      for (int r = 0; r < 4; ++r)
        Gb[(size_t)(chunk * CCH + ct * 64 + 32 * wc + 16 * m + 4 * lg + r) * CCH +
           dt * 64 + 32 * wd + 16 * f + lr] = acc[m][f][r];
}

// K5: reduce Gpart over chunks, scale, softmax over d -> S
__global__ __launch_bounds__(64) void k5_softmax(
    const float* __restrict__ Gpart, const float* __restrict__ invn,
    const float* __restrict__ sigma, float* __restrict__ S)
{
  int c = blockIdx.x, z = blockIdx.y;
  const float* Gb = Gpart + (size_t)z * SPLIT * CCH * CCH;
  const float* inb = invn + (size_t)z * 384;
  float sig = sigma[0];
  float ink = inb[192 + c];
  float lv[3];
#pragma unroll
  for (int r = 0; r < 3; ++r) {
    int d = threadIdx.x + 64 * r;
    float s = 0.f;
    for (int ch = 0; ch < SPLIT; ++ch)
      s += Gb[(size_t)(ch * CCH + c) * CCH + d];
    lv[r] = s * ink * inb[d] * sig;
  }
  float m = fmaxf(lv[0], fmaxf(lv[1], lv[2]));
  m = wmax(m);
  float e[3], tot = 0.f;
#pragma unroll
  for (int r = 0; r < 3; ++r) { e[r] = __expf(lv[r] - m); tot += e[r]; }
  tot = wsum(tot);
  float inv = 1.f / tot;
  float* Sb = S + (size_t)z * CCH * CCH;
#pragma unroll
  for (int r = 0; r < 3; ++r) Sb[(size_t)c * CCH + threadIdx.x + 64 * r] = e[r] * inv;
}

// K6: Mt[e][c] = sum_d S[c][d] * Wlin[d][e]  (bf16 out, row-major, for K7 B-side)
__global__ __launch_bounds__(192) void k6_mlin(
    const float* __restrict__ S, const float* __restrict__ Wlin, ushort* __restrict__ Mt)
{
  int z = blockIdx.y, c = blockIdx.x, e = threadIdx.x;
  const float* Sb = S + (size_t)z * CCH * CCH;
  float s = 0.f;
  for (int d = 0; d < CCH; ++d) s += Sb[(size_t)c * CCH + d] * Wlin[(size_t)d * CCH + e];
  Mt[(size_t)z * CCH * CCH + (size_t)e * CCH + c] = f2bf(s);
}

// K7: out[e][n] = sum_c Mt[e][c] * Vt2[n][c]. LDS-free; ALL loads hoisted.
__global__ __launch_bounds__(256, 2) void k7_out(
    const ushort* __restrict__ Mt, const ushort* __restrict__ Vt2, float* __restrict__ out)
{
  int z = blockIdx.z;
  const ushort* Mb = Mt + (size_t)z * CCH * CCH;
  const ushort* Vb2 = Vt2 + (size_t)z * HWN * CCH;
  float* ob = out + (size_t)z * CCH * HWN;
  int nt = blockIdx.x, et = blockIdx.y;
  int e0 = et * 64, n0 = nt * 128;
  int t = threadIdx.x, l = t & 63, w = t >> 6;
  int wn = w >> 1, we = w & 1, lg = l >> 4, lr = l & 15;
  int nblk = n0 >> 4;
  bf16x8 mfrag[2][3][2];
#pragma unroll
  for (int h = 0; h < 2; ++h)
#pragma unroll
    for (int k3 = 0; k3 < 3; ++k3)
#pragma unroll
      for (int mg = 0; mg < 2; ++mg)
        mfrag[h][k3][mg] = *reinterpret_cast<const bf16x8*>(
            &Mb[(size_t)(e0 + 32 * we + 16 * mg + lr) * CCH + 96 * h + 32 * k3 + 8 * lg]);
  bf16x8 an[2][3][4];
#pragma unroll
  for (int h = 0; h < 2; ++h)
#pragma unroll
    for (int k3 = 0; k3 < 3; ++k3)
#pragma unroll
      for (int ng = 0; ng < 4; ++ng)
        an[h][k3][ng] = *reinterpret_cast<const bf16x8*>(
            &Vb2[(size_t)(nblk + 4 * wn + ng) * (16 * CCH) + (12 * h + 4 * k3 + lg) * 128 + lr * 8]);
  f32x4 acc[4][2] = {};   // [ng][mg]: n = 64wn+16ng+4lg+r, e = 32we+16mg+lr
#pragma unroll
  for (int h = 0; h < 2; ++h)
#pragma unroll
    for (int k3 = 0; k3 < 3; ++k3)
#pragma unroll
      for (int ng = 0; ng < 4; ++ng)
#pragma unroll
        for (int mg = 0; mg < 2; ++mg)
          acc[ng][mg] = __builtin_amdgcn_mfma_f32_16x16x32_bf16(an[h][k3][ng], mfrag[h][k3][mg], acc[ng][mg], 0, 0, 0);
#pragma unroll
  for (int ng = 0; ng < 4; ++ng)
#pragma unroll
    for (int mg = 0; mg < 2; ++mg)
      *reinterpret_cast<f32x4*>(
          &ob[(size_t)(e0 + 32 * we + 16 * mg + lr) * HWN + n0 + 64 * wn + 16 * ng + 4 * lg]) = acc[ng][mg];
}

extern "C" void kernel_launch(void* const* d_in, const int* in_sizes, int n_in,
                              void* d_out, int out_size, void* d_ws, size_t ws_size,
                              hipStream_t stream) {
  const float* x     = (const float*)d_in[0];
  const float* Wqkv  = (const float*)d_in[1];
  const float* Wlin  = (const float*)d_in[2];
  const float* sigma = (const float*)d_in[3];
  float* out = (float*)d_out;

  const size_t wbElems = (size_t)576 * CCH;
  const size_t perB =
      (size_t)HWN * CCH * 2 +          // xT2
      (size_t)384 * HWN * 2 +          // Tqk2
      (size_t)HWN * CCH * 2 +          // Vt2
      (size_t)256 * 384 * 4 +          // norm2p
      (size_t)384 * 4 +                // invn
      (size_t)SPLIT * CCH * CCH * 4 +  // Gpart
      (size_t)CCH * CCH * 4 +          // S
      (size_t)CCH * CCH * 2;           // Mt
  int per = (ws_size >= wbElems * 2 + (size_t)NB * perB) ? NB : 1;

  ushort* Wb = (ushort*)d_ws;
  k0_wconv<<<dim3(9, 3), 256, 0, stream>>>(Wqkv, Wb);

  for (int b0 = 0; b0 < NB; b0 += per) {
    char* base = (char*)d_ws + wbElems * 2;
    ushort* xT2  = (ushort*)base;
    ushort* Tqk2 = xT2 + (size_t)per * HWN * CCH;
    ushort* Vt2  = Tqk2 + (size_t)per * 384 * HWN;
    float* norm2p = (float*)(Vt2 + (size_t)per * HWN * CCH);
    float* invn  = norm2p + (size_t)per * 256 * 384;
    float* Gpart = invn + (size_t)per * 384;
    float* S     = Gpart + (size_t)per * SPLIT * CCH * CCH;
    ushort* Mt   = (ushort*)(S + (size_t)per * CCH * CCH);
    const float* xb = x + (size_t)b0 * CCH * HWN;
    float* ob = out + (size_t)b0 * CCH * HWN;

    k1_xpose  <<<dim3(256, 3, per), 256, 0, stream>>>(xb, xT2);
    k2_qkv    <<<dim3(128, 9, per), 256, 0, stream>>>(xT2, Wb, Tqk2, Vt2, norm2p);
    k3_invn   <<<dim3(384, per), 256, 0, stream>>>(norm2p, invn);
    k4_gram   <<<dim3(9, SPLIT, per), 256, 0, stream>>>(Tqk2, Gpart);
    k5_softmax<<<dim3(192, per), 64, 0, stream>>>(Gpart, invn, sigma, S);
    k6_mlin   <<<dim3(192, per), 192, 0, stream>>>(S, Wlin, Mt);
    k7_out    <<<dim3(128, 3, per), 256, 0, stream>>>(Mt, Vt2, ob);
  }
}